// Round 10
// baseline (420.384 us; speedup 1.0000x reference)
//
#include <hip/hip_runtime.h>

// NCM via bf16-split MFMA — R7 pipeline (192us) with L2 switched to
// ELEM-SPLIT to remove barrier B2 (3 -> 2 barriers/node):
//   L1: wave = N-tile (feats 16w..+15), all 64 elems       [unchanged]
//   L2: wave = ELEM-tile (elems 16w..+15), ALL 64 feats    [NEW]
//   L3: wave = elem-tile (elems 16w..+15), 16 out-feats    [unchanged]
// h2 is now wave-local (written and read by the same wave) -> L3 follows L2
// with only an lgkmcnt wait, no s_barrier; waves skew freely so one wave's
// L3 overlaps another's L2. The L2 MFMA tiles are byte-identical fragments
// (same weight rows x same elem k-slices), just executed on a different
// wave => bit-identical output. w2f grows 6 -> 24 frags (+72 VGPR, fits
// 2 waves/SIMD). Prefetch: L1(i) issues W3(i)+u(i+1); post-B1 issues
// W1(i+1)+stage-xu; after L2 MFMAs issues W2(i+1).

#define BT 64

typedef __attribute__((ext_vector_type(8))) short bf16x8;
typedef __attribute__((ext_vector_type(4))) float f32x4;
#define MFMA16 __builtin_amdgcn_mfma_f32_16x16x32_bf16

// ws layout (u16 units), per node i (stride 33792):
//   W1' [3][64 n][96 k]  @ 0      (k 0..63 parents, 64..79 exo, 80..95 zero)
//   W2' [3][64 n][64 k]  @ 18432
//   W3' [3][16 n][64 k]  @ 30720
#define NODE_STRIDE 33792
#define W1_SPLIT    6144
#define W2_OFF      18432
#define W2_SPLIT    4096
#define W3_OFF      30720
#define W3_SPLIT    1024

__device__ inline unsigned short bf16_rne(float x) {
    unsigned u = __float_as_uint(x);
    u += 0x7fffu + ((u >> 16) & 1u);
    return (unsigned short)(u >> 16);
}
__device__ inline float bf16_tof(unsigned short h) {
    return __uint_as_float(((unsigned)h) << 16);
}
__device__ inline void split3(float x, unsigned short& h, unsigned short& m,
                              unsigned short& l) {
    h = bf16_rne(x);
    float r = x - bf16_tof(h);      // exact (Sterbenz)
    m = bf16_rne(r);
    float r2 = r - bf16_tof(m);     // exact
    l = bf16_rne(r2);
}

// Packed pair split: v_cvt_pk_bf16_f32 is RNE (default MODE) == bf16_rne for
// all finite inputs. D.lo = bf16(a), D.hi = bf16(b).
__device__ inline unsigned cvt_pk_bf16(float a, float b) {
    unsigned d;
    asm("v_cvt_pk_bf16_f32 %0, %1, %2" : "=v"(d) : "v"(a), "v"(b));
    return d;
}
__device__ inline void split3_pair(float a, float b,
                                   unsigned& h, unsigned& m, unsigned& l) {
    h = cvt_pk_bf16(a, b);
    float ra = a - __uint_as_float(h << 16);          // exact
    float rb = b - __uint_as_float(h & 0xffff0000u);  // exact
    m = cvt_pk_bf16(ra, rb);
    float sa = ra - __uint_as_float(m << 16);         // exact
    float sb = rb - __uint_as_float(m & 0xffff0000u); // exact
    l = cvt_pk_bf16(sa, sb);
}

// XOR chunk-swizzle for h buffers: 128B row = 8 chunks of 16B; physical
// chunk = logical chunk ^ (e&7). feat in u16 units; returns u16 index in row.
__device__ inline int hswz(int e, int feat) {
    return (feat & 7) | ((((feat >> 3) ^ e) & 7) << 3);
}

// Relaxed barrier: drain LDS only; global loads/stores stay in flight.
__device__ inline void bar_lgkm() {
    asm volatile("s_waitcnt lgkmcnt(0)\n\ts_barrier" ::: "memory");
}

// ---------------- prep: split weights into ws (unchanged) ----------------
#define PER_NODE_ITEMS (64 * 96 + 64 * 64 + 16 * 64)  // 11264

__global__ void prep_weights(const float* __restrict__ w_r1,
                             const float* __restrict__ w_r2,
                             const float* __restrict__ w_r3,
                             const float* __restrict__ w_i1,
                             const float* __restrict__ w_i2,
                             const float* __restrict__ w_i3,
                             unsigned short* __restrict__ ws) {
    int tid = blockIdx.x * 256 + threadIdx.x;
    if (tid >= 32 * PER_NODE_ITEMS) return;
    int node = tid / PER_NODE_ITEMS;
    int r = tid - node * PER_NODE_ITEMS;
    int off, stride;
    float wv = 0.0f;
    if (r < 6144) {                       // W1': n,k in [64][96]
        int n = r / 96, k = r - n * 96;
        if (k < 64) {
            wv = (node >= 4) ? w_i1[((node - 4) * 80 + k) * 64 + n] : 0.0f;
        } else if (k < 80) {
            wv = (node < 4) ? w_r1[(node * 16 + (k - 64)) * 64 + n]
                            : w_i1[((node - 4) * 80 + k) * 64 + n];
        } // else zero pad
        off = n * 96 + k; stride = W1_SPLIT;
    } else if (r < 10240) {               // W2': [64][64]
        int r2 = r - 6144;
        int n = r2 >> 6, k = r2 & 63;
        wv = (node < 4) ? w_r2[(node * 64 + k) * 64 + n]
                        : w_i2[((node - 4) * 64 + k) * 64 + n];
        off = W2_OFF + n * 64 + k; stride = W2_SPLIT;
    } else {                              // W3': [16][64]
        int r3 = r - 10240;
        int n = r3 >> 6, k = r3 & 63;
        wv = (node < 4) ? w_r3[(node * 64 + k) * 16 + n]
                        : w_i3[((node - 4) * 64 + k) * 16 + n];
        off = W3_OFF + n * 64 + k; stride = W3_SPLIT;
    }
    unsigned short h, m, l;
    split3(wv, h, m, l);
    unsigned short* base = ws + node * NODE_STRIDE;
    base[off] = h;
    base[off + stride] = m;
    base[off + 2 * stride] = l;
}

// -------- weight prefetch macros (compile-time indices only) --------
#define LOAD_W1(nn) do {                                                      \
    const unsigned short* Wb_ = ws + (long)(nn) * NODE_STRIDE + n1 * 96;      \
    _Pragma("unroll") for (int g_ = 0; g_ < 2; ++g_) {                        \
        const unsigned short* wp_ = Wb_ + g_ * 32 + lq * 8;                   \
        w1f[g_ * 3 + 0] = *(const bf16x8*)(wp_);                              \
        w1f[g_ * 3 + 1] = *(const bf16x8*)(wp_ + W1_SPLIT);                   \
        w1f[g_ * 3 + 2] = *(const bf16x8*)(wp_ + 2 * W1_SPLIT);               \
    }                                                                         \
    const unsigned short* we_ = Wb_ + 64 + lq * 8;                            \
    w1f[6] = *(const bf16x8*)(we_);                                           \
    w1f[7] = *(const bf16x8*)(we_ + W1_SPLIT);                                \
    w1f[8] = *(const bf16x8*)(we_ + 2 * W1_SPLIT);                            \
} while (0)

// Elem-split L2: every wave loads W2 rows for ALL 4 feat tiles.
#define LOAD_W2(nn) do {                                                      \
    _Pragma("unroll") for (int nt_ = 0; nt_ < 4; ++nt_) {                     \
        const unsigned short* Wb_ = ws + (long)(nn) * NODE_STRIDE + W2_OFF    \
                                    + (nt_ * 16 + lr) * 64;                   \
        _Pragma("unroll") for (int g_ = 0; g_ < 2; ++g_) {                    \
            const unsigned short* wp_ = Wb_ + g_ * 32 + lq * 8;               \
            w2f[nt_ * 6 + g_ * 3 + 0] = *(const bf16x8*)(wp_);                \
            w2f[nt_ * 6 + g_ * 3 + 1] = *(const bf16x8*)(wp_ + W2_SPLIT);     \
            w2f[nt_ * 6 + g_ * 3 + 2] = *(const bf16x8*)(wp_ + 2 * W2_SPLIT); \
        }                                                                     \
    }                                                                         \
} while (0)

#define LOAD_W3(nn) do {                                                      \
    const unsigned short* Wb_ =                                               \
        ws + (long)(nn) * NODE_STRIDE + W3_OFF + lr * 64;                     \
    _Pragma("unroll") for (int g_ = 0; g_ < 2; ++g_) {                        \
        const unsigned short* wp_ = Wb_ + g_ * 32 + lq * 8;                   \
        w3f[g_ * 3 + 0] = *(const bf16x8*)(wp_);                              \
        w3f[g_ * 3 + 1] = *(const bf16x8*)(wp_ + W3_SPLIT);                   \
        w3f[g_ * 3 + 2] = *(const bf16x8*)(wp_ + 2 * W3_SPLIT);               \
    }                                                                         \
} while (0)

#define STAGE_XU(uv) do {                                                     \
    unsigned hS0_, mS0_, lS0_, hS1_, mS1_, lS1_;                              \
    split3_pair((uv).x, (uv).y, hS0_, mS0_, lS0_);                            \
    split3_pair((uv).z, (uv).w, hS1_, mS1_, lS1_);                            \
    *(uint2*)&xu[0][l][4 * w] = make_uint2(hS0_, hS1_);                       \
    *(uint2*)&xu[1][l][4 * w] = make_uint2(mS0_, mS1_);                       \
    *(uint2*)&xu[2][l][4 * w] = make_uint2(lS0_, lS1_);                       \
} while (0)

// ---------------- main kernel ----------------
__global__ __launch_bounds__(256, 2) void ncm_mfma(
    const float* __restrict__ u,
    const unsigned short* __restrict__ ws,
    const float* __restrict__ b_r1, const float* __restrict__ b_r2,
    const float* __restrict__ b_r3, const float* __restrict__ b_i1,
    const float* __restrict__ b_i2, const float* __restrict__ b_i3,
    float* __restrict__ out)
{
    __shared__ __align__(16) unsigned short ring[4][64][24]; // parent bits
    __shared__ __align__(16) unsigned short xu[3][64][40];   // exo splits, 80B rows
    __shared__ __align__(16) unsigned short h1s[3][64][64];  // [split][elem][feat-swz]
    __shared__ __align__(16) unsigned short h2s[3][64][64];

    const int tid = threadIdx.x;
    const int l   = tid & 63;
    const int w   = tid >> 6;     // wave 0..3
    const int lr  = l & 15;       // frag row/col index
    const int lq  = l >> 4;       // quad 0..3 (k-slice / feat sub-group)
    const int n1  = 16 * w + lr;  // this wave's weight row (out feat), L1
    const int e2  = 16 * w + lr;  // this wave's elem row, L2/L3

    const long eg = (long)blockIdx.x * BT;
    const float* u_blk = u + eg * 512;

    bf16x8 w1f[9], w2f[24], w3f[6];  // in-flight weight fragments

    // ---- prologue: prefetch node-0 W1/W2, stage node-0 xu ----
    LOAD_W1(0);
    LOAD_W2(0);
    {
        float4 uv = *(const float4*)(u_blk + (long)l * 512 + w * 4);
        STAGE_XU(uv);
    }
    bar_lgkm();

    for (int i = 0; i < 32; ++i) {
        const int nn = (i < 31) ? i + 1 : 31;   // clamped next node
        f32x4 acc[4] = {{0,0,0,0},{0,0,0,0},{0,0,0,0},{0,0,0,0}};

        // ================= Phase P1: L1 =================
        LOAD_W3(i);                 // consumed at L3(i), ~1.5 phases away
        float4 uN;
        if (i < 31)                 // u for node i+1, staged post-B1
            uN = *(const float4*)(u_blk + (long)l * 512 + nn * 16 + w * 4);

        if (i >= 4) {   // parent region, K = 64 (4 parents x 16)
            #pragma unroll
            for (int g = 0; g < 2; ++g) {
                const int f = g * 32 + lq * 8;
                const int slot = (i + (f >> 4)) & 3;   // ring slot of parent
                #pragma unroll
                for (int m = 0; m < 4; ++m) {
                    bf16x8 ab = *(const bf16x8*)&ring[slot][m * 16 + lr][f & 15];
                    acc[m] = MFMA16(w1f[g * 3 + 0], ab, acc[m], 0, 0, 0);
                    acc[m] = MFMA16(w1f[g * 3 + 1], ab, acc[m], 0, 0, 0);
                    acc[m] = MFMA16(w1f[g * 3 + 2], ab, acc[m], 0, 0, 0);
                }
            }
        }
        {   // exo region: B-frag k 0..15 real (lq<2, from xu), 16..31 zero
            #pragma unroll
            for (int m = 0; m < 4; ++m) {
                bf16x8 a0 = {}, a1 = {}, a2 = {};
                if (lq < 2) {
                    const int e = m * 16 + lr;
                    a0 = *(const bf16x8*)&xu[0][e][lq * 8];
                    a1 = *(const bf16x8*)&xu[1][e][lq * 8];
                    a2 = *(const bf16x8*)&xu[2][e][lq * 8];
                }
                acc[m] = MFMA16(w1f[6], a0, acc[m], 0, 0, 0);
                acc[m] = MFMA16(w1f[7], a0, acc[m], 0, 0, 0);
                acc[m] = MFMA16(w1f[8], a0, acc[m], 0, 0, 0);
                acc[m] = MFMA16(w1f[6], a1, acc[m], 0, 0, 0);
                acc[m] = MFMA16(w1f[7], a1, acc[m], 0, 0, 0);
                acc[m] = MFMA16(w1f[8], a1, acc[m], 0, 0, 0);
                acc[m] = MFMA16(w1f[6], a2, acc[m], 0, 0, 0);
                acc[m] = MFMA16(w1f[7], a2, acc[m], 0, 0, 0);
            }
        }
        {   // L1 epilogue: lane holds feats 16w+4lq..+3 of elem m*16+lr
            const float* B1 = (i < 4) ? (b_r1 + i * 64) : (b_i1 + (i - 4) * 64);
            float4 bv = *(const float4*)(B1 + 16 * w + 4 * lq);
            const int fo = 16 * w + 4 * lq;
            #pragma unroll
            for (int m = 0; m < 4; ++m) {
                const int e = m * 16 + lr;
                float v0 = fmaxf(acc[m][0] + bv.x, 0.0f);
                float v1 = fmaxf(acc[m][1] + bv.y, 0.0f);
                float v2 = fmaxf(acc[m][2] + bv.z, 0.0f);
                float v3 = fmaxf(acc[m][3] + bv.w, 0.0f);
                unsigned hP0, mP0, lP0, hP1, mP1, lP1;
                split3_pair(v0, v1, hP0, mP0, lP0);
                split3_pair(v2, v3, hP1, mP1, lP1);
                const int o = hswz(e, fo);
                *(uint2*)&h1s[0][e][o] = make_uint2(hP0, hP1);
                *(uint2*)&h1s[1][e][o] = make_uint2(mP0, mP1);
                *(uint2*)&h1s[2][e][o] = make_uint2(lP0, lP1);
            }
        }
        bar_lgkm();   // B1: h1s complete

        // ============ Phase P2: L2 (elem-split) + L3, no barrier between ===
        LOAD_W1(nn);                // w1f free since L1(i); used L1(i+1)
        if (i < 31) STAGE_XU(uN);   // xu free since B1; visible after B3

        #pragma unroll
        for (int m = 0; m < 4; ++m) acc[m] = (f32x4){0, 0, 0, 0};
        {
            #pragma unroll
            for (int g = 0; g < 2; ++g) {
                const int f = g * 32 + lq * 8;
                const int o = hswz(e2, f);
                bf16x8 a0 = *(const bf16x8*)&h1s[0][e2][o];
                bf16x8 a1 = *(const bf16x8*)&h1s[1][e2][o];
                bf16x8 a2 = *(const bf16x8*)&h1s[2][e2][o];
                #pragma unroll
                for (int nt = 0; nt < 4; ++nt) {
                    acc[nt] = MFMA16(w2f[nt * 6 + g * 3 + 0], a0, acc[nt], 0, 0, 0);
                    acc[nt] = MFMA16(w2f[nt * 6 + g * 3 + 1], a0, acc[nt], 0, 0, 0);
                    acc[nt] = MFMA16(w2f[nt * 6 + g * 3 + 2], a0, acc[nt], 0, 0, 0);
                    acc[nt] = MFMA16(w2f[nt * 6 + g * 3 + 0], a1, acc[nt], 0, 0, 0);
                    acc[nt] = MFMA16(w2f[nt * 6 + g * 3 + 1], a1, acc[nt], 0, 0, 0);
                    acc[nt] = MFMA16(w2f[nt * 6 + g * 3 + 2], a1, acc[nt], 0, 0, 0);
                    acc[nt] = MFMA16(w2f[nt * 6 + g * 3 + 0], a2, acc[nt], 0, 0, 0);
                    acc[nt] = MFMA16(w2f[nt * 6 + g * 3 + 1], a2, acc[nt], 0, 0, 0);
                }
            }
        }
        LOAD_W2(nn);                // w2f consumed above; used L2(i+1)
        {   // L2 epilogue: lane holds feats nt*16+4lq..+3 of its own elem e2
            const float* B2 = (i < 4) ? (b_r2 + i * 64) : (b_i2 + (i - 4) * 64);
            #pragma unroll
            for (int nt = 0; nt < 4; ++nt) {
                float4 bv = *(const float4*)(B2 + 16 * nt + 4 * lq);
                float v0 = fmaxf(acc[nt][0] + bv.x, 0.0f);
                float v1 = fmaxf(acc[nt][1] + bv.y, 0.0f);
                float v2 = fmaxf(acc[nt][2] + bv.z, 0.0f);
                float v3 = fmaxf(acc[nt][3] + bv.w, 0.0f);
                unsigned hP0, mP0, lP0, hP1, mP1, lP1;
                split3_pair(v0, v1, hP0, mP0, lP0);
                split3_pair(v2, v3, hP1, mP1, lP1);
                const int o = hswz(e2, 16 * nt + 4 * lq);
                *(uint2*)&h2s[0][e2][o] = make_uint2(hP0, hP1);
                *(uint2*)&h2s[1][e2][o] = make_uint2(mP0, mP1);
                *(uint2*)&h2s[2][e2][o] = make_uint2(lP0, lP1);
            }
        }
        // h2s for this wave's elems is wave-local: compiler orders the
        // ds_write -> ds_read via lgkmcnt; no s_barrier needed.
        {   // L3: this wave's 16 elems x 16 out-feats
            f32x4 c3 = {0, 0, 0, 0};
            #pragma unroll
            for (int g = 0; g < 2; ++g) {
                const int f = g * 32 + lq * 8;
                const int o = hswz(e2, f);
                bf16x8 a0 = *(const bf16x8*)&h2s[0][e2][o];
                bf16x8 a1 = *(const bf16x8*)&h2s[1][e2][o];
                bf16x8 a2 = *(const bf16x8*)&h2s[2][e2][o];
                c3 = MFMA16(w3f[g * 3 + 0], a0, c3, 0, 0, 0);
                c3 = MFMA16(w3f[g * 3 + 1], a0, c3, 0, 0, 0);
                c3 = MFMA16(w3f[g * 3 + 2], a0, c3, 0, 0, 0);
                c3 = MFMA16(w3f[g * 3 + 0], a1, c3, 0, 0, 0);
                c3 = MFMA16(w3f[g * 3 + 1], a1, c3, 0, 0, 0);
                c3 = MFMA16(w3f[g * 3 + 2], a1, c3, 0, 0, 0);
                c3 = MFMA16(w3f[g * 3 + 0], a2, c3, 0, 0, 0);
                c3 = MFMA16(w3f[g * 3 + 1], a2, c3, 0, 0, 0);
            }
            const float* B3 = (i < 4) ? (b_r3 + i * 16) : (b_i3 + (i - 4) * 16);
            float4 bv = *(const float4*)(B3 + 4 * lq);
            float v0 = c3[0] + bv.x;
            float v1 = c3[1] + bv.y;
            float v2 = c3[2] + bv.z;
            float v3 = c3[3] + bv.w;
            *(float4*)(out + (eg + e2) * 512 + i * 16 + 4 * lq) =
                make_float4(v0, v1, v2, v3);
            const int slot = i & 3;
            unsigned r0 = (v0 > 0.5f ? 0x3F80u : 0u) |
                          ((v1 > 0.5f ? 0x3F80u : 0u) << 16);
            unsigned r1 = (v2 > 0.5f ? 0x3F80u : 0u) |
                          ((v3 > 0.5f ? 0x3F80u : 0u) << 16);
            *(uint2*)&ring[slot][e2][4 * lq] = make_uint2(r0, r1);
        }
        bar_lgkm();   // B3: ring+xu visible; h buffers free for next node
    }
}

extern "C" void kernel_launch(void* const* d_in, const int* in_sizes, int n_in,
                              void* d_out, int out_size, void* d_ws, size_t ws_size,
                              hipStream_t stream) {
    const float* u    = (const float*)d_in[0];
    const float* w_r1 = (const float*)d_in[1];
    const float* b_r1 = (const float*)d_in[2];
    const float* w_r2 = (const float*)d_in[3];
    const float* b_r2 = (const float*)d_in[4];
    const float* w_r3 = (const float*)d_in[5];
    const float* b_r3 = (const float*)d_in[6];
    const float* w_i1 = (const float*)d_in[7];
    const float* b_i1 = (const float*)d_in[8];
    const float* w_i2 = (const float*)d_in[9];
    const float* b_i2 = (const float*)d_in[10];
    const float* w_i3 = (const float*)d_in[11];
    const float* b_i3 = (const float*)d_in[12];
    float* out = (float*)d_out;
    unsigned short* ws = (unsigned short*)d_ws;

    prep_weights<<<dim3((32 * PER_NODE_ITEMS) / 256), dim3(256), 0, stream>>>(
        w_r1, w_r2, w_r3, w_i1, w_i2, w_i3, ws);

    ncm_mfma<<<dim3(512), dim3(256), 0, stream>>>(
        u, ws, b_r1, b_r2, b_r3, b_i1, b_i2, b_i3, out);
}

// Round 11
// 287.957 us; speedup vs baseline: 1.4599x; 1.4599x over previous
//
#include <hip/hip_runtime.h>

// NCM via bf16-split MFMA — exact R7 structure (192us: BT=64, grid 512,
// 4 waves, 3 relaxed barriers/node, reg weight prefetch) + two additive,
// bit-identical tweaks:
//  (T1) P3(i) prefetches L1(i+1)'s g=0 ring fragments (parents i-3,i-2;
//       slots (i+1)&3,(i+2)&3 — final since B3(i-2), disjoint from L3(i)'s
//       slot i&3) into 4 regs -> P1 opens with 12 ready MFMAs, no ds wait.
//  (T2) s_setprio(1) around MFMA clusters (2 independent blocks/CU give the
//       scheduler role diversity to arbitrate).
// MFMA product order per accumulator element unchanged => bit-identical.

#define BT 64

typedef __attribute__((ext_vector_type(8))) short bf16x8;
typedef __attribute__((ext_vector_type(4))) float f32x4;
#define MFMA16 __builtin_amdgcn_mfma_f32_16x16x32_bf16

// ws layout (u16 units), per node i (stride 33792):
//   W1' [3][64 n][96 k]  @ 0      (k 0..63 parents, 64..79 exo, 80..95 zero)
//   W2' [3][64 n][64 k]  @ 18432
//   W3' [3][16 n][64 k]  @ 30720
#define NODE_STRIDE 33792
#define W1_SPLIT    6144
#define W2_OFF      18432
#define W2_SPLIT    4096
#define W3_OFF      30720
#define W3_SPLIT    1024

__device__ inline unsigned short bf16_rne(float x) {
    unsigned u = __float_as_uint(x);
    u += 0x7fffu + ((u >> 16) & 1u);
    return (unsigned short)(u >> 16);
}
__device__ inline float bf16_tof(unsigned short h) {
    return __uint_as_float(((unsigned)h) << 16);
}
__device__ inline void split3(float x, unsigned short& h, unsigned short& m,
                              unsigned short& l) {
    h = bf16_rne(x);
    float r = x - bf16_tof(h);      // exact (Sterbenz)
    m = bf16_rne(r);
    float r2 = r - bf16_tof(m);     // exact
    l = bf16_rne(r2);
}

// Packed pair split: v_cvt_pk_bf16_f32 is RNE (default MODE) == bf16_rne for
// all finite inputs. D.lo = bf16(a), D.hi = bf16(b).
__device__ inline unsigned cvt_pk_bf16(float a, float b) {
    unsigned d;
    asm("v_cvt_pk_bf16_f32 %0, %1, %2" : "=v"(d) : "v"(a), "v"(b));
    return d;
}
__device__ inline void split3_pair(float a, float b,
                                   unsigned& h, unsigned& m, unsigned& l) {
    h = cvt_pk_bf16(a, b);
    float ra = a - __uint_as_float(h << 16);          // exact
    float rb = b - __uint_as_float(h & 0xffff0000u);  // exact
    m = cvt_pk_bf16(ra, rb);
    float sa = ra - __uint_as_float(m << 16);         // exact
    float sb = rb - __uint_as_float(m & 0xffff0000u); // exact
    l = cvt_pk_bf16(sa, sb);
}

// XOR chunk-swizzle for h buffers: 128B row = 8 chunks of 16B; physical
// chunk = logical chunk ^ (e&7). feat in u16 units; returns u16 index in row.
__device__ inline int hswz(int e, int feat) {
    return (feat & 7) | ((((feat >> 3) ^ e) & 7) << 3);
}

// Relaxed barrier: drain LDS only; global loads/stores stay in flight.
__device__ inline void bar_lgkm() {
    asm volatile("s_waitcnt lgkmcnt(0)\n\ts_barrier" ::: "memory");
}

// ---------------- prep: split weights into ws (unchanged) ----------------
#define PER_NODE_ITEMS (64 * 96 + 64 * 64 + 16 * 64)  // 11264

__global__ void prep_weights(const float* __restrict__ w_r1,
                             const float* __restrict__ w_r2,
                             const float* __restrict__ w_r3,
                             const float* __restrict__ w_i1,
                             const float* __restrict__ w_i2,
                             const float* __restrict__ w_i3,
                             unsigned short* __restrict__ ws) {
    int tid = blockIdx.x * 256 + threadIdx.x;
    if (tid >= 32 * PER_NODE_ITEMS) return;
    int node = tid / PER_NODE_ITEMS;
    int r = tid - node * PER_NODE_ITEMS;
    int off, stride;
    float wv = 0.0f;
    if (r < 6144) {                       // W1': n,k in [64][96]
        int n = r / 96, k = r - n * 96;
        if (k < 64) {
            wv = (node >= 4) ? w_i1[((node - 4) * 80 + k) * 64 + n] : 0.0f;
        } else if (k < 80) {
            wv = (node < 4) ? w_r1[(node * 16 + (k - 64)) * 64 + n]
                            : w_i1[((node - 4) * 80 + k) * 64 + n];
        } // else zero pad
        off = n * 96 + k; stride = W1_SPLIT;
    } else if (r < 10240) {               // W2': [64][64]
        int r2 = r - 6144;
        int n = r2 >> 6, k = r2 & 63;
        wv = (node < 4) ? w_r2[(node * 64 + k) * 64 + n]
                        : w_i2[((node - 4) * 64 + k) * 64 + n];
        off = W2_OFF + n * 64 + k; stride = W2_SPLIT;
    } else {                              // W3': [16][64]
        int r3 = r - 10240;
        int n = r3 >> 6, k = r3 & 63;
        wv = (node < 4) ? w_r3[(node * 64 + k) * 16 + n]
                        : w_i3[((node - 4) * 64 + k) * 16 + n];
        off = W3_OFF + n * 64 + k; stride = W3_SPLIT;
    }
    unsigned short h, m, l;
    split3(wv, h, m, l);
    unsigned short* base = ws + node * NODE_STRIDE;
    base[off] = h;
    base[off + stride] = m;
    base[off + 2 * stride] = l;
}

// -------- weight prefetch macros (compile-time indices only) --------
#define LOAD_W1(nn) do {                                                      \
    const unsigned short* Wb_ = ws + (long)(nn) * NODE_STRIDE + n1 * 96;      \
    _Pragma("unroll") for (int g_ = 0; g_ < 2; ++g_) {                        \
        const unsigned short* wp_ = Wb_ + g_ * 32 + lq * 8;                   \
        w1f[g_ * 3 + 0] = *(const bf16x8*)(wp_);                              \
        w1f[g_ * 3 + 1] = *(const bf16x8*)(wp_ + W1_SPLIT);                   \
        w1f[g_ * 3 + 2] = *(const bf16x8*)(wp_ + 2 * W1_SPLIT);               \
    }                                                                         \
    const unsigned short* we_ = Wb_ + 64 + lq * 8;                            \
    w1f[6] = *(const bf16x8*)(we_);                                           \
    w1f[7] = *(const bf16x8*)(we_ + W1_SPLIT);                                \
    w1f[8] = *(const bf16x8*)(we_ + 2 * W1_SPLIT);                            \
} while (0)

#define LOAD_W2(nn) do {                                                      \
    const unsigned short* Wb_ =                                               \
        ws + (long)(nn) * NODE_STRIDE + W2_OFF + n1 * 64;                     \
    _Pragma("unroll") for (int g_ = 0; g_ < 2; ++g_) {                        \
        const unsigned short* wp_ = Wb_ + g_ * 32 + lq * 8;                   \
        w2f[g_ * 3 + 0] = *(const bf16x8*)(wp_);                              \
        w2f[g_ * 3 + 1] = *(const bf16x8*)(wp_ + W2_SPLIT);                   \
        w2f[g_ * 3 + 2] = *(const bf16x8*)(wp_ + 2 * W2_SPLIT);               \
    }                                                                         \
} while (0)

#define LOAD_W3(nn) do {                                                      \
    const unsigned short* Wb_ =                                               \
        ws + (long)(nn) * NODE_STRIDE + W3_OFF + lr * 64;                     \
    _Pragma("unroll") for (int g_ = 0; g_ < 2; ++g_) {                        \
        w3f[g_ * 3 + 0] = *(const bf16x8*)(Wb_ + g_ * 32 + lq * 8);           \
        w3f[g_ * 3 + 1] = *(const bf16x8*)(Wb_ + g_ * 32 + lq * 8 + W3_SPLIT);\
        w3f[g_ * 3 + 2] = *(const bf16x8*)(Wb_ + g_ * 32 + lq * 8             \
                                           + 2 * W3_SPLIT);                   \
    }                                                                         \
} while (0)

#define STAGE_XU(uv) do {                                                     \
    unsigned hS0_, mS0_, lS0_, hS1_, mS1_, lS1_;                              \
    split3_pair((uv).x, (uv).y, hS0_, mS0_, lS0_);                            \
    split3_pair((uv).z, (uv).w, hS1_, mS1_, lS1_);                            \
    *(uint2*)&xu[0][l][4 * w] = make_uint2(hS0_, hS1_);                       \
    *(uint2*)&xu[1][l][4 * w] = make_uint2(mS0_, mS1_);                       \
    *(uint2*)&xu[2][l][4 * w] = make_uint2(lS0_, lS1_);                       \
} while (0)

// ---------------- main kernel ----------------
__global__ __launch_bounds__(256, 2) void ncm_mfma(
    const float* __restrict__ u,
    const unsigned short* __restrict__ ws,
    const float* __restrict__ b_r1, const float* __restrict__ b_r2,
    const float* __restrict__ b_r3, const float* __restrict__ b_i1,
    const float* __restrict__ b_i2, const float* __restrict__ b_i3,
    float* __restrict__ out)
{
    __shared__ __align__(16) unsigned short ring[4][64][24]; // parent bits
    __shared__ __align__(16) unsigned short xu[3][64][40];   // exo splits, 80B rows
    __shared__ __align__(16) unsigned short h1s[3][64][64];  // [split][elem][feat-swz]
    __shared__ __align__(16) unsigned short h2s[3][64][64];

    const int tid = threadIdx.x;
    const int l   = tid & 63;
    const int w   = tid >> 6;     // wave 0..3
    const int lr  = l & 15;       // frag row/col index
    const int lq  = l >> 4;       // quad 0..3 (k-slice / feat sub-group)
    const int n1  = 16 * w + lr;  // this wave's weight row (out feat), L1/L2

    const long eg = (long)blockIdx.x * BT;
    const float* u_blk = u + eg * 512;

    bf16x8 w1f[9], w2f[6], w3f[6];   // in-flight weight fragments
    bf16x8 rb0[4];                   // prefetched g=0 ring frags for next node

    // ---- prologue: prefetch node-0 W1/W2, stage node-0 xu ----
    LOAD_W1(0);
    LOAD_W2(0);
    {
        float4 uv = *(const float4*)(u_blk + (long)l * 512 + w * 4);
        STAGE_XU(uv);
    }
    bar_lgkm();

    for (int i = 0; i < 32; ++i) {
        const int nn = (i < 31) ? i + 1 : 31;   // clamped next node
        f32x4 acc[4] = {{0,0,0,0},{0,0,0,0},{0,0,0,0},{0,0,0,0}};

        // ================= Phase L1 =================
        LOAD_W3(i);                 // consumed at L3(i), 2 barriers away
        float4 uN;
        if (i < 31)                 // u for node i+1, split at L2(i)
            uN = *(const float4*)(u_blk + (long)l * 512 + nn * 16 + w * 4);

        if (i >= 4) {   // parent region, K = 64 (4 parents x 16)
            __builtin_amdgcn_s_setprio(1);
            // g=0: parents i-4, i-3 — fragments prefetched at P3(i-1)
            #pragma unroll
            for (int m = 0; m < 4; ++m) {
                acc[m] = MFMA16(w1f[0], rb0[m], acc[m], 0, 0, 0);
                acc[m] = MFMA16(w1f[1], rb0[m], acc[m], 0, 0, 0);
                acc[m] = MFMA16(w1f[2], rb0[m], acc[m], 0, 0, 0);
            }
            {   // g=1: parents i-2, i-1 (slot written up to L3(i-1))
                const int f = 32 + lq * 8;
                const int slot = (i + (f >> 4)) & 3;
                #pragma unroll
                for (int m = 0; m < 4; ++m) {
                    bf16x8 ab = *(const bf16x8*)&ring[slot][m * 16 + lr][f & 15];
                    acc[m] = MFMA16(w1f[3], ab, acc[m], 0, 0, 0);
                    acc[m] = MFMA16(w1f[4], ab, acc[m], 0, 0, 0);
                    acc[m] = MFMA16(w1f[5], ab, acc[m], 0, 0, 0);
                }
            }
            __builtin_amdgcn_s_setprio(0);
        }
        {   // exo region: B-frag k 0..15 real (lq<2, from xu), 16..31 zero
            __builtin_amdgcn_s_setprio(1);
            #pragma unroll
            for (int m = 0; m < 4; ++m) {
                bf16x8 a0 = {}, a1 = {}, a2 = {};
                if (lq < 2) {
                    const int e = m * 16 + lr;
                    a0 = *(const bf16x8*)&xu[0][e][lq * 8];
                    a1 = *(const bf16x8*)&xu[1][e][lq * 8];
                    a2 = *(const bf16x8*)&xu[2][e][lq * 8];
                }
                acc[m] = MFMA16(w1f[6], a0, acc[m], 0, 0, 0);
                acc[m] = MFMA16(w1f[7], a0, acc[m], 0, 0, 0);
                acc[m] = MFMA16(w1f[8], a0, acc[m], 0, 0, 0);
                acc[m] = MFMA16(w1f[6], a1, acc[m], 0, 0, 0);
                acc[m] = MFMA16(w1f[7], a1, acc[m], 0, 0, 0);
                acc[m] = MFMA16(w1f[8], a1, acc[m], 0, 0, 0);
                acc[m] = MFMA16(w1f[6], a2, acc[m], 0, 0, 0);
                acc[m] = MFMA16(w1f[7], a2, acc[m], 0, 0, 0);
            }
            __builtin_amdgcn_s_setprio(0);
        }
        {   // L1 epilogue: lane holds feats 16w+4lq..+3 of elem m*16+lr
            const float* B1 = (i < 4) ? (b_r1 + i * 64) : (b_i1 + (i - 4) * 64);
            float4 bv = *(const float4*)(B1 + 16 * w + 4 * lq);
            const int fo = 16 * w + 4 * lq;
            #pragma unroll
            for (int m = 0; m < 4; ++m) {
                const int e = m * 16 + lr;
                float v0 = fmaxf(acc[m][0] + bv.x, 0.0f);
                float v1 = fmaxf(acc[m][1] + bv.y, 0.0f);
                float v2 = fmaxf(acc[m][2] + bv.z, 0.0f);
                float v3 = fmaxf(acc[m][3] + bv.w, 0.0f);
                unsigned hP0, mP0, lP0, hP1, mP1, lP1;
                split3_pair(v0, v1, hP0, mP0, lP0);
                split3_pair(v2, v3, hP1, mP1, lP1);
                const int o = hswz(e, fo);
                *(uint2*)&h1s[0][e][o] = make_uint2(hP0, hP1);
                *(uint2*)&h1s[1][e][o] = make_uint2(mP0, mP1);
                *(uint2*)&h1s[2][e][o] = make_uint2(lP0, lP1);
            }
        }
        bar_lgkm();   // B1: h1s complete

        // ================= Phase L2 =================
        LOAD_W1(nn);                // consumed at L1(i+1), 2 barriers away
        if (i < 31) STAGE_XU(uN);   // xu free since B1; visible after B3

        #pragma unroll
        for (int m = 0; m < 4; ++m) acc[m] = (f32x4){0, 0, 0, 0};
        {
            __builtin_amdgcn_s_setprio(1);
            #pragma unroll
            for (int g = 0; g < 2; ++g) {
                const int f = g * 32 + lq * 8;
                #pragma unroll
                for (int m = 0; m < 4; ++m) {
                    const int e = m * 16 + lr;
                    const int o = hswz(e, f);
                    bf16x8 a0 = *(const bf16x8*)&h1s[0][e][o];
                    bf16x8 a1 = *(const bf16x8*)&h1s[1][e][o];
                    bf16x8 a2 = *(const bf16x8*)&h1s[2][e][o];
                    acc[m] = MFMA16(w2f[g * 3 + 0], a0, acc[m], 0, 0, 0);
                    acc[m] = MFMA16(w2f[g * 3 + 1], a0, acc[m], 0, 0, 0);
                    acc[m] = MFMA16(w2f[g * 3 + 2], a0, acc[m], 0, 0, 0);
                    acc[m] = MFMA16(w2f[g * 3 + 0], a1, acc[m], 0, 0, 0);
                    acc[m] = MFMA16(w2f[g * 3 + 1], a1, acc[m], 0, 0, 0);
                    acc[m] = MFMA16(w2f[g * 3 + 2], a1, acc[m], 0, 0, 0);
                    acc[m] = MFMA16(w2f[g * 3 + 0], a2, acc[m], 0, 0, 0);
                    acc[m] = MFMA16(w2f[g * 3 + 1], a2, acc[m], 0, 0, 0);
                }
            }
            __builtin_amdgcn_s_setprio(0);
        }
        {   // L2 epilogue
            const float* B2 = (i < 4) ? (b_r2 + i * 64) : (b_i2 + (i - 4) * 64);
            float4 bv = *(const float4*)(B2 + 16 * w + 4 * lq);
            const int fo = 16 * w + 4 * lq;
            #pragma unroll
            for (int m = 0; m < 4; ++m) {
                const int e = m * 16 + lr;
                float v0 = fmaxf(acc[m][0] + bv.x, 0.0f);
                float v1 = fmaxf(acc[m][1] + bv.y, 0.0f);
                float v2 = fmaxf(acc[m][2] + bv.z, 0.0f);
                float v3 = fmaxf(acc[m][3] + bv.w, 0.0f);
                unsigned hP0, mP0, lP0, hP1, mP1, lP1;
                split3_pair(v0, v1, hP0, mP0, lP0);
                split3_pair(v2, v3, hP1, mP1, lP1);
                const int o = hswz(e, fo);
                *(uint2*)&h2s[0][e][o] = make_uint2(hP0, hP1);
                *(uint2*)&h2s[1][e][o] = make_uint2(mP0, mP1);
                *(uint2*)&h2s[2][e][o] = make_uint2(lP0, lP1);
            }
        }
        bar_lgkm();   // B2: h2s complete

        // ================= Phase L3 =================
        LOAD_W2(nn);                // consumed at L2(i+1), 2 barriers away
        // T1: prefetch L1(nn)'s g=0 ring frags (parents nn-4, nn-3; slots
        // (nn)&3,(nn+1)&3 — final since B3(nn-3), disjoint from L3(i)'s
        // slot i&3 writes).
        if (i >= 3 && i < 31) {
            const int f = lq * 8;
            const int slot = (nn + (f >> 4)) & 3;
            #pragma unroll
            for (int m = 0; m < 4; ++m)
                rb0[m] = *(const bf16x8*)&ring[slot][m * 16 + lr][f & 15];
        }
        {
            f32x4 c3 = {0, 0, 0, 0};
            const int e = 16 * w + lr;
            __builtin_amdgcn_s_setprio(1);
            #pragma unroll
            for (int g = 0; g < 2; ++g) {
                const int f = g * 32 + lq * 8;
                const int o = hswz(e, f);
                bf16x8 a0 = *(const bf16x8*)&h2s[0][e][o];
                bf16x8 a1 = *(const bf16x8*)&h2s[1][e][o];
                bf16x8 a2 = *(const bf16x8*)&h2s[2][e][o];
                c3 = MFMA16(w3f[g * 3 + 0], a0, c3, 0, 0, 0);
                c3 = MFMA16(w3f[g * 3 + 1], a0, c3, 0, 0, 0);
                c3 = MFMA16(w3f[g * 3 + 2], a0, c3, 0, 0, 0);
                c3 = MFMA16(w3f[g * 3 + 0], a1, c3, 0, 0, 0);
                c3 = MFMA16(w3f[g * 3 + 1], a1, c3, 0, 0, 0);
                c3 = MFMA16(w3f[g * 3 + 2], a1, c3, 0, 0, 0);
                c3 = MFMA16(w3f[g * 3 + 0], a2, c3, 0, 0, 0);
                c3 = MFMA16(w3f[g * 3 + 1], a2, c3, 0, 0, 0);
            }
            __builtin_amdgcn_s_setprio(0);
            const float* B3 = (i < 4) ? (b_r3 + i * 16) : (b_i3 + (i - 4) * 16);
            float4 bv = *(const float4*)(B3 + 4 * lq);
            float v0 = c3[0] + bv.x;
            float v1 = c3[1] + bv.y;
            float v2 = c3[2] + bv.z;
            float v3 = c3[3] + bv.w;
            *(float4*)(out + (eg + e) * 512 + i * 16 + 4 * lq) =
                make_float4(v0, v1, v2, v3);
            const int slot = i & 3;
            unsigned r0 = (v0 > 0.5f ? 0x3F80u : 0u) |
                          ((v1 > 0.5f ? 0x3F80u : 0u) << 16);
            unsigned r1 = (v2 > 0.5f ? 0x3F80u : 0u) |
                          ((v3 > 0.5f ? 0x3F80u : 0u) << 16);
            *(uint2*)&ring[slot][e][4 * lq] = make_uint2(r0, r1);
        }
        bar_lgkm();   // B3: ring+xu visible; h buffers free for next node
    }
}

extern "C" void kernel_launch(void* const* d_in, const int* in_sizes, int n_in,
                              void* d_out, int out_size, void* d_ws, size_t ws_size,
                              hipStream_t stream) {
    const float* u    = (const float*)d_in[0];
    const float* w_r1 = (const float*)d_in[1];
    const float* b_r1 = (const float*)d_in[2];
    const float* w_r2 = (const float*)d_in[3];
    const float* b_r2 = (const float*)d_in[4];
    const float* w_r3 = (const float*)d_in[5];
    const float* b_r3 = (const float*)d_in[6];
    const float* w_i1 = (const float*)d_in[7];
    const float* b_i1 = (const float*)d_in[8];
    const float* w_i2 = (const float*)d_in[9];
    const float* b_i2 = (const float*)d_in[10];
    const float* w_i3 = (const float*)d_in[11];
    const float* b_i3 = (const float*)d_in[12];
    float* out = (float*)d_out;
    unsigned short* ws = (unsigned short*)d_ws;

    prep_weights<<<dim3((32 * PER_NODE_ITEMS) / 256), dim3(256), 0, stream>>>(
        w_r1, w_r2, w_r3, w_i1, w_i2, w_i3, ws);

    ncm_mfma<<<dim3(512), dim3(256), 0, stream>>>(
        u, ws, b_r1, b_r2, b_r3, b_i1, b_i2, b_i3, out);
}

// Round 12
// 278.974 us; speedup vs baseline: 1.5069x; 1.0322x over previous
//
#include <hip/hip_runtime.h>

// NCM via bf16-split MFMA — exact R7 pipeline (192us: BT=64, grid 512,
// 4 waves, 3 relaxed barriers/node, reg weight prefetch), with two
// bit-identical overhead cuts (R11's setprio/ring-prefetch reverted: null):
//  (1) h1s/h2s swizzle REMOVED; rows padded to 72 u16 (144B). Bank profile
//      unchanged (2-way, free), but ds addresses become base+immediate —
//      kills the per-access XOR address chains. xu shrunk to 24-u16 rows
//      (48B, 16B-aligned, 2-way) so LDS stays exactly 76800B -> 2 blocks/CU.
//  (2) u-stage remap: thread t stages elem t>>2, feats (t&3)*4 — quads of
//      threads share one 64B line -> 16 txns/wave-load instead of 64.
// No arithmetic reordered anywhere => bit-identical output.

#define BT 64

typedef __attribute__((ext_vector_type(8))) short bf16x8;
typedef __attribute__((ext_vector_type(4))) float f32x4;
#define MFMA16 __builtin_amdgcn_mfma_f32_16x16x32_bf16

// ws layout (u16 units), per node i (stride 33792):
//   W1' [3][64 n][96 k]  @ 0      (k 0..63 parents, 64..79 exo, 80..95 zero)
//   W2' [3][64 n][64 k]  @ 18432
//   W3' [3][16 n][64 k]  @ 30720
#define NODE_STRIDE 33792
#define W1_SPLIT    6144
#define W2_OFF      18432
#define W2_SPLIT    4096
#define W3_OFF      30720
#define W3_SPLIT    1024

__device__ inline unsigned short bf16_rne(float x) {
    unsigned u = __float_as_uint(x);
    u += 0x7fffu + ((u >> 16) & 1u);
    return (unsigned short)(u >> 16);
}
__device__ inline float bf16_tof(unsigned short h) {
    return __uint_as_float(((unsigned)h) << 16);
}
__device__ inline void split3(float x, unsigned short& h, unsigned short& m,
                              unsigned short& l) {
    h = bf16_rne(x);
    float r = x - bf16_tof(h);      // exact (Sterbenz)
    m = bf16_rne(r);
    float r2 = r - bf16_tof(m);     // exact
    l = bf16_rne(r2);
}

// Packed pair split: v_cvt_pk_bf16_f32 is RNE (default MODE) == bf16_rne for
// all finite inputs. D.lo = bf16(a), D.hi = bf16(b).
__device__ inline unsigned cvt_pk_bf16(float a, float b) {
    unsigned d;
    asm("v_cvt_pk_bf16_f32 %0, %1, %2" : "=v"(d) : "v"(a), "v"(b));
    return d;
}
__device__ inline void split3_pair(float a, float b,
                                   unsigned& h, unsigned& m, unsigned& l) {
    h = cvt_pk_bf16(a, b);
    float ra = a - __uint_as_float(h << 16);          // exact
    float rb = b - __uint_as_float(h & 0xffff0000u);  // exact
    m = cvt_pk_bf16(ra, rb);
    float sa = ra - __uint_as_float(m << 16);         // exact
    float sb = rb - __uint_as_float(m & 0xffff0000u); // exact
    l = cvt_pk_bf16(sa, sb);
}

// Relaxed barrier: drain LDS only; global loads/stores stay in flight.
__device__ inline void bar_lgkm() {
    asm volatile("s_waitcnt lgkmcnt(0)\n\ts_barrier" ::: "memory");
}

// ---------------- prep: split weights into ws (unchanged) ----------------
#define PER_NODE_ITEMS (64 * 96 + 64 * 64 + 16 * 64)  // 11264

__global__ void prep_weights(const float* __restrict__ w_r1,
                             const float* __restrict__ w_r2,
                             const float* __restrict__ w_r3,
                             const float* __restrict__ w_i1,
                             const float* __restrict__ w_i2,
                             const float* __restrict__ w_i3,
                             unsigned short* __restrict__ ws) {
    int tid = blockIdx.x * 256 + threadIdx.x;
    if (tid >= 32 * PER_NODE_ITEMS) return;
    int node = tid / PER_NODE_ITEMS;
    int r = tid - node * PER_NODE_ITEMS;
    int off, stride;
    float wv = 0.0f;
    if (r < 6144) {                       // W1': n,k in [64][96]
        int n = r / 96, k = r - n * 96;
        if (k < 64) {
            wv = (node >= 4) ? w_i1[((node - 4) * 80 + k) * 64 + n] : 0.0f;
        } else if (k < 80) {
            wv = (node < 4) ? w_r1[(node * 16 + (k - 64)) * 64 + n]
                            : w_i1[((node - 4) * 80 + k) * 64 + n];
        } // else zero pad
        off = n * 96 + k; stride = W1_SPLIT;
    } else if (r < 10240) {               // W2': [64][64]
        int r2 = r - 6144;
        int n = r2 >> 6, k = r2 & 63;
        wv = (node < 4) ? w_r2[(node * 64 + k) * 64 + n]
                        : w_i2[((node - 4) * 64 + k) * 64 + n];
        off = W2_OFF + n * 64 + k; stride = W2_SPLIT;
    } else {                              // W3': [16][64]
        int r3 = r - 10240;
        int n = r3 >> 6, k = r3 & 63;
        wv = (node < 4) ? w_r3[(node * 64 + k) * 16 + n]
                        : w_i3[((node - 4) * 64 + k) * 16 + n];
        off = W3_OFF + n * 64 + k; stride = W3_SPLIT;
    }
    unsigned short h, m, l;
    split3(wv, h, m, l);
    unsigned short* base = ws + node * NODE_STRIDE;
    base[off] = h;
    base[off + stride] = m;
    base[off + 2 * stride] = l;
}

// -------- weight prefetch macros (compile-time indices only) --------
#define LOAD_W1(nn) do {                                                      \
    const unsigned short* Wb_ = ws + (long)(nn) * NODE_STRIDE + n1 * 96;      \
    _Pragma("unroll") for (int g_ = 0; g_ < 2; ++g_) {                        \
        const unsigned short* wp_ = Wb_ + g_ * 32 + lq * 8;                   \
        w1f[g_ * 3 + 0] = *(const bf16x8*)(wp_);                              \
        w1f[g_ * 3 + 1] = *(const bf16x8*)(wp_ + W1_SPLIT);                   \
        w1f[g_ * 3 + 2] = *(const bf16x8*)(wp_ + 2 * W1_SPLIT);               \
    }                                                                         \
    const unsigned short* we_ = Wb_ + 64 + lq * 8;                            \
    w1f[6] = *(const bf16x8*)(we_);                                           \
    w1f[7] = *(const bf16x8*)(we_ + W1_SPLIT);                                \
    w1f[8] = *(const bf16x8*)(we_ + 2 * W1_SPLIT);                            \
} while (0)

#define LOAD_W2(nn) do {                                                      \
    const unsigned short* Wb_ =                                               \
        ws + (long)(nn) * NODE_STRIDE + W2_OFF + n1 * 64;                     \
    _Pragma("unroll") for (int g_ = 0; g_ < 2; ++g_) {                        \
        const unsigned short* wp_ = Wb_ + g_ * 32 + lq * 8;                   \
        w2f[g_ * 3 + 0] = *(const bf16x8*)(wp_);                              \
        w2f[g_ * 3 + 1] = *(const bf16x8*)(wp_ + W2_SPLIT);                   \
        w2f[g_ * 3 + 2] = *(const bf16x8*)(wp_ + 2 * W2_SPLIT);               \
    }                                                                         \
} while (0)

#define LOAD_W3(nn) do {                                                      \
    const unsigned short* Wb_ =                                               \
        ws + (long)(nn) * NODE_STRIDE + W3_OFF + lr * 64;                     \
    _Pragma("unroll") for (int g_ = 0; g_ < 2; ++g_) {                        \
        w3f[g_ * 3 + 0] = *(const bf16x8*)(Wb_ + g_ * 32 + lq * 8);           \
        w3f[g_ * 3 + 1] = *(const bf16x8*)(Wb_ + g_ * 32 + lq * 8 + W3_SPLIT);\
        w3f[g_ * 3 + 2] = *(const bf16x8*)(Wb_ + g_ * 32 + lq * 8             \
                                           + 2 * W3_SPLIT);                   \
    }                                                                         \
} while (0)

// Stage: thread t splits feats (t&3)*4..+3 of elem t>>2 (quad-coalesced).
#define STAGE_XU(uv) do {                                                     \
    unsigned hS0_, mS0_, lS0_, hS1_, mS1_, lS1_;                              \
    split3_pair((uv).x, (uv).y, hS0_, mS0_, lS0_);                            \
    split3_pair((uv).z, (uv).w, hS1_, mS1_, lS1_);                            \
    *(uint2*)&xu[0][se][sf] = make_uint2(hS0_, hS1_);                         \
    *(uint2*)&xu[1][se][sf] = make_uint2(mS0_, mS1_);                         \
    *(uint2*)&xu[2][se][sf] = make_uint2(lS0_, lS1_);                         \
} while (0)

// ---------------- main kernel ----------------
__global__ __launch_bounds__(256, 2) void ncm_mfma(
    const float* __restrict__ u,
    const unsigned short* __restrict__ ws,
    const float* __restrict__ b_r1, const float* __restrict__ b_r2,
    const float* __restrict__ b_r3, const float* __restrict__ b_i1,
    const float* __restrict__ b_i2, const float* __restrict__ b_i3,
    float* __restrict__ out)
{
    __shared__ __align__(16) unsigned short ring[4][64][24]; // parent bits
    __shared__ __align__(16) unsigned short xu[3][64][24];   // exo splits, 48B rows
    __shared__ __align__(16) unsigned short h1s[3][64][72];  // padded, no swizzle
    __shared__ __align__(16) unsigned short h2s[3][64][72];
    // LDS: 12288 + 9216 + 27648 + 27648 = 76800B -> 2 blocks/CU (same as R7)

    const int tid = threadIdx.x;
    const int l   = tid & 63;
    const int w   = tid >> 6;     // wave 0..3
    const int lr  = l & 15;       // frag row/col index
    const int lq  = l >> 4;       // quad 0..3 (k-slice / feat sub-group)
    const int n1  = 16 * w + lr;  // this wave's weight row (out feat), L1/L2
    const int se  = tid >> 2;     // stage elem 0..63
    const int sf  = (tid & 3) * 4;// stage feat base 0,4,8,12

    const long eg = (long)blockIdx.x * BT;
    const float* u_blk = u + eg * 512;

    bf16x8 w1f[9], w2f[6], w3f[6];   // in-flight weight fragments

    // ---- prologue: prefetch node-0 W1/W2, stage node-0 xu ----
    LOAD_W1(0);
    LOAD_W2(0);
    {
        float4 uv = *(const float4*)(u_blk + (long)se * 512 + sf);
        STAGE_XU(uv);
    }
    bar_lgkm();

    for (int i = 0; i < 32; ++i) {
        const int nn = (i < 31) ? i + 1 : 31;   // clamped next node
        f32x4 acc[4] = {{0,0,0,0},{0,0,0,0},{0,0,0,0},{0,0,0,0}};

        // ================= Phase L1 =================
        LOAD_W3(i);                 // consumed at L3(i), 2 barriers away
        float4 uN;
        if (i < 31)                 // u for node i+1, split at L2(i)
            uN = *(const float4*)(u_blk + (long)se * 512 + nn * 16 + sf);

        if (i >= 4) {   // parent region, K = 64 (4 parents x 16)
            #pragma unroll
            for (int g = 0; g < 2; ++g) {
                const int f = g * 32 + lq * 8;
                const int slot = (i + (f >> 4)) & 3;   // ring slot of parent
                #pragma unroll
                for (int m = 0; m < 4; ++m) {
                    bf16x8 ab = *(const bf16x8*)&ring[slot][m * 16 + lr][f & 15];
                    acc[m] = MFMA16(w1f[g * 3 + 0], ab, acc[m], 0, 0, 0);
                    acc[m] = MFMA16(w1f[g * 3 + 1], ab, acc[m], 0, 0, 0);
                    acc[m] = MFMA16(w1f[g * 3 + 2], ab, acc[m], 0, 0, 0);
                }
            }
        }
        {   // exo region: B-frag k 0..15 real (lq<2, from xu), 16..31 zero
            #pragma unroll
            for (int m = 0; m < 4; ++m) {
                bf16x8 a0 = {}, a1 = {}, a2 = {};
                if (lq < 2) {
                    const int e = m * 16 + lr;
                    a0 = *(const bf16x8*)&xu[0][e][lq * 8];
                    a1 = *(const bf16x8*)&xu[1][e][lq * 8];
                    a2 = *(const bf16x8*)&xu[2][e][lq * 8];
                }
                acc[m] = MFMA16(w1f[6], a0, acc[m], 0, 0, 0);
                acc[m] = MFMA16(w1f[7], a0, acc[m], 0, 0, 0);
                acc[m] = MFMA16(w1f[8], a0, acc[m], 0, 0, 0);
                acc[m] = MFMA16(w1f[6], a1, acc[m], 0, 0, 0);
                acc[m] = MFMA16(w1f[7], a1, acc[m], 0, 0, 0);
                acc[m] = MFMA16(w1f[8], a1, acc[m], 0, 0, 0);
                acc[m] = MFMA16(w1f[6], a2, acc[m], 0, 0, 0);
                acc[m] = MFMA16(w1f[7], a2, acc[m], 0, 0, 0);
            }
        }
        {   // L1 epilogue: lane holds feats 16w+4lq..+3 of elem m*16+lr
            const float* B1 = (i < 4) ? (b_r1 + i * 64) : (b_i1 + (i - 4) * 64);
            float4 bv = *(const float4*)(B1 + 16 * w + 4 * lq);
            const int fo = 16 * w + 4 * lq;
            #pragma unroll
            for (int m = 0; m < 4; ++m) {
                const int e = m * 16 + lr;
                float v0 = fmaxf(acc[m][0] + bv.x, 0.0f);
                float v1 = fmaxf(acc[m][1] + bv.y, 0.0f);
                float v2 = fmaxf(acc[m][2] + bv.z, 0.0f);
                float v3 = fmaxf(acc[m][3] + bv.w, 0.0f);
                unsigned hP0, mP0, lP0, hP1, mP1, lP1;
                split3_pair(v0, v1, hP0, mP0, lP0);
                split3_pair(v2, v3, hP1, mP1, lP1);
                *(uint2*)&h1s[0][e][fo] = make_uint2(hP0, hP1);
                *(uint2*)&h1s[1][e][fo] = make_uint2(mP0, mP1);
                *(uint2*)&h1s[2][e][fo] = make_uint2(lP0, lP1);
            }
        }
        bar_lgkm();   // B1: h1s complete

        // ================= Phase L2 =================
        LOAD_W1(nn);                // consumed at L1(i+1), 2 barriers away
        if (i < 31) STAGE_XU(uN);   // xu free since B1; visible after B3

        #pragma unroll
        for (int m = 0; m < 4; ++m) acc[m] = (f32x4){0, 0, 0, 0};
        {
            #pragma unroll
            for (int g = 0; g < 2; ++g) {
                const int f = g * 32 + lq * 8;
                #pragma unroll
                for (int m = 0; m < 4; ++m) {
                    const int e = m * 16 + lr;
                    bf16x8 a0 = *(const bf16x8*)&h1s[0][e][f];
                    bf16x8 a1 = *(const bf16x8*)&h1s[1][e][f];
                    bf16x8 a2 = *(const bf16x8*)&h1s[2][e][f];
                    acc[m] = MFMA16(w2f[g * 3 + 0], a0, acc[m], 0, 0, 0);
                    acc[m] = MFMA16(w2f[g * 3 + 1], a0, acc[m], 0, 0, 0);
                    acc[m] = MFMA16(w2f[g * 3 + 2], a0, acc[m], 0, 0, 0);
                    acc[m] = MFMA16(w2f[g * 3 + 0], a1, acc[m], 0, 0, 0);
                    acc[m] = MFMA16(w2f[g * 3 + 1], a1, acc[m], 0, 0, 0);
                    acc[m] = MFMA16(w2f[g * 3 + 2], a1, acc[m], 0, 0, 0);
                    acc[m] = MFMA16(w2f[g * 3 + 0], a2, acc[m], 0, 0, 0);
                    acc[m] = MFMA16(w2f[g * 3 + 1], a2, acc[m], 0, 0, 0);
                }
            }
        }
        {   // L2 epilogue
            const float* B2 = (i < 4) ? (b_r2 + i * 64) : (b_i2 + (i - 4) * 64);
            float4 bv = *(const float4*)(B2 + 16 * w + 4 * lq);
            const int fo = 16 * w + 4 * lq;
            #pragma unroll
            for (int m = 0; m < 4; ++m) {
                const int e = m * 16 + lr;
                float v0 = fmaxf(acc[m][0] + bv.x, 0.0f);
                float v1 = fmaxf(acc[m][1] + bv.y, 0.0f);
                float v2 = fmaxf(acc[m][2] + bv.z, 0.0f);
                float v3 = fmaxf(acc[m][3] + bv.w, 0.0f);
                unsigned hP0, mP0, lP0, hP1, mP1, lP1;
                split3_pair(v0, v1, hP0, mP0, lP0);
                split3_pair(v2, v3, hP1, mP1, lP1);
                *(uint2*)&h2s[0][e][fo] = make_uint2(hP0, hP1);
                *(uint2*)&h2s[1][e][fo] = make_uint2(mP0, mP1);
                *(uint2*)&h2s[2][e][fo] = make_uint2(lP0, lP1);
            }
        }
        bar_lgkm();   // B2: h2s complete

        // ================= Phase L3 =================
        LOAD_W2(nn);                // consumed at L2(i+1), 2 barriers away
        {
            f32x4 c3 = {0, 0, 0, 0};
            const int e = 16 * w + lr;
            #pragma unroll
            for (int g = 0; g < 2; ++g) {
                const int f = g * 32 + lq * 8;
                bf16x8 a0 = *(const bf16x8*)&h2s[0][e][f];
                bf16x8 a1 = *(const bf16x8*)&h2s[1][e][f];
                bf16x8 a2 = *(const bf16x8*)&h2s[2][e][f];
                c3 = MFMA16(w3f[g * 3 + 0], a0, c3, 0, 0, 0);
                c3 = MFMA16(w3f[g * 3 + 1], a0, c3, 0, 0, 0);
                c3 = MFMA16(w3f[g * 3 + 2], a0, c3, 0, 0, 0);
                c3 = MFMA16(w3f[g * 3 + 0], a1, c3, 0, 0, 0);
                c3 = MFMA16(w3f[g * 3 + 1], a1, c3, 0, 0, 0);
                c3 = MFMA16(w3f[g * 3 + 2], a1, c3, 0, 0, 0);
                c3 = MFMA16(w3f[g * 3 + 0], a2, c3, 0, 0, 0);
                c3 = MFMA16(w3f[g * 3 + 1], a2, c3, 0, 0, 0);
            }
            const float* B3 = (i < 4) ? (b_r3 + i * 16) : (b_i3 + (i - 4) * 16);
            float4 bv = *(const float4*)(B3 + 4 * lq);
            float v0 = c3[0] + bv.x;
            float v1 = c3[1] + bv.y;
            float v2 = c3[2] + bv.z;
            float v3 = c3[3] + bv.w;
            *(float4*)(out + (eg + e) * 512 + i * 16 + 4 * lq) =
                make_float4(v0, v1, v2, v3);
            const int slot = i & 3;
            unsigned r0 = (v0 > 0.5f ? 0x3F80u : 0u) |
                          ((v1 > 0.5f ? 0x3F80u : 0u) << 16);
            unsigned r1 = (v2 > 0.5f ? 0x3F80u : 0u) |
                          ((v3 > 0.5f ? 0x3F80u : 0u) << 16);
            *(uint2*)&ring[slot][e][4 * lq] = make_uint2(r0, r1);
        }
        bar_lgkm();   // B3: ring+xu visible; h buffers free for next node
    }
}

extern "C" void kernel_launch(void* const* d_in, const int* in_sizes, int n_in,
                              void* d_out, int out_size, void* d_ws, size_t ws_size,
                              hipStream_t stream) {
    const float* u    = (const float*)d_in[0];
    const float* w_r1 = (const float*)d_in[1];
    const float* b_r1 = (const float*)d_in[2];
    const float* w_r2 = (const float*)d_in[3];
    const float* b_r2 = (const float*)d_in[4];
    const float* w_r3 = (const float*)d_in[5];
    const float* b_r3 = (const float*)d_in[6];
    const float* w_i1 = (const float*)d_in[7];
    const float* b_i1 = (const float*)d_in[8];
    const float* w_i2 = (const float*)d_in[9];
    const float* b_i2 = (const float*)d_in[10];
    const float* w_i3 = (const float*)d_in[11];
    const float* b_i3 = (const float*)d_in[12];
    float* out = (float*)d_out;
    unsigned short* ws = (unsigned short*)d_ws;

    prep_weights<<<dim3((32 * PER_NODE_ITEMS) / 256), dim3(256), 0, stream>>>(
        w_r1, w_r2, w_r3, w_i1, w_i2, w_i3, ws);

    ncm_mfma<<<dim3(512), dim3(256), 0, stream>>>(
        u, ws, b_r1, b_r2, b_r3, b_i1, b_i2, b_i3, out);
}